// Round 1
// baseline (806.505 us; speedup 1.0000x reference)
//
#include <hip/hip_runtime.h>
#include <math.h>

#define N_NODES 100000
#define N_EDGES 1600000
#define F_INF 128
#define HIDF 128
#define NCLS 40
#define BN_EPS 1e-5f
#define SCAN_NB ((N_NODES + 1023) / 1024)

// ---------------- degree / dinv ----------------
__global__ void deg_kernel(const int* __restrict__ ei, int* __restrict__ deg) {
    int e = blockIdx.x * 256 + threadIdx.x;
    if (e < N_EDGES) atomicAdd(&deg[ei[N_EDGES + e]], 1);
}

__global__ void dinv_kernel(const int* __restrict__ deg, float* __restrict__ dinv) {
    int i = blockIdx.x * 256 + threadIdx.x;
    if (i < N_NODES) dinv[i] = rsqrtf((float)(deg[i] + 1));  // +1 self loop
}

// ---------------- exclusive scan of counts (deg[i]+1) ----------------
__global__ void scan1_kernel(const int* __restrict__ deg, int* __restrict__ bsum) {
    __shared__ int sdata[256];
    int b = blockIdx.x;
    int base = b * 1024;
    int s = 0;
    for (int t = threadIdx.x; t < 1024; t += 256) {
        int i = base + t;
        if (i < N_NODES) s += deg[i] + 1;
    }
    sdata[threadIdx.x] = s;
    __syncthreads();
    for (int o = 128; o >= 1; o >>= 1) {
        if (threadIdx.x < o) sdata[threadIdx.x] += sdata[threadIdx.x + o];
        __syncthreads();
    }
    if (threadIdx.x == 0) bsum[b] = sdata[0];
}

__global__ void scan2_kernel(int* __restrict__ bsum, int* __restrict__ offs) {
    if (threadIdx.x == 0) {
        int acc = 0;
        for (int b = 0; b < SCAN_NB; ++b) {
            int v = bsum[b];
            bsum[b] = acc;
            acc += v;
        }
        offs[N_NODES] = acc;  // == N_EDGES + N_NODES
    }
}

__global__ void scan3_kernel(const int* __restrict__ deg, const int* __restrict__ bsum,
                             int* __restrict__ offs, int* __restrict__ cursor) {
    __shared__ int sthr[256];
    int b = blockIdx.x, tid = threadIdx.x;
    int base = b * 1024 + tid * 4;
    int c[4];
    int s = 0;
    #pragma unroll
    for (int j = 0; j < 4; ++j) {
        int i = base + j;
        c[j] = (i < N_NODES) ? (deg[i] + 1) : 0;
        s += c[j];
    }
    sthr[tid] = s;
    __syncthreads();
    for (int o = 1; o < 256; o <<= 1) {
        int t = (tid >= o) ? sthr[tid - o] : 0;
        __syncthreads();
        sthr[tid] += t;
        __syncthreads();
    }
    int o0 = bsum[b] + sthr[tid] - s;  // exclusive prefix for this thread's 4 items
    #pragma unroll
    for (int j = 0; j < 4; ++j) {
        int i = base + j;
        if (i < N_NODES) {
            offs[i] = o0;
            cursor[i] = o0;
            o0 += c[j];
        }
    }
}

__global__ void fill_kernel(const int* __restrict__ ei, int* __restrict__ cursor,
                            int* __restrict__ csr) {
    int e = blockIdx.x * 256 + threadIdx.x;
    if (e < N_EDGES) {
        int src = ei[e];
        int dst = ei[N_EDGES + e];
        int p = atomicAdd(&cursor[dst], 1);
        csr[p] = src;
    } else if (e < N_EDGES + N_NODES) {
        int i = e - N_EDGES;
        int p = atomicAdd(&cursor[i], 1);
        csr[p] = i;  // self loop
    }
}

// ---------------- GEMM: Y[M x LD] = foldX(X[M x 128]) @ W[128 x LD] ----------------
// fold: x' = relu(a[k]*x + c[k]) with a=ac[0..127], c=ac[128..255]
template <bool FOLD, int LD>
__global__ __launch_bounds__(256) void gemm_kernel(const float* __restrict__ X,
                                                   const float* __restrict__ Wm,
                                                   const float* __restrict__ ac,
                                                   float* __restrict__ Y) {
    __shared__ float sW[128][64];   // 32 KB : W[k][bn0+c]
    __shared__ float sX[64][128];   // 32 KB
    const int tid = threadIdx.x;
    const int row0 = blockIdx.x * 64;
    const int bn0 = blockIdx.y * 64;

    // stage W slice (zero-pad beyond LD)
    for (int t = tid; t < 128 * 16; t += 256) {
        int k = t >> 4, c4 = (t & 15) * 4;
        int c = bn0 + c4;
        float4 v = make_float4(0.f, 0.f, 0.f, 0.f);
        if (c + 4 <= LD) v = *(const float4*)(Wm + (size_t)k * LD + c);
        *(float4*)&sW[k][c4] = v;
    }
    // stage X tile (optionally BN+ReLU folded)
    for (int t = tid; t < 64 * 32; t += 256) {
        int r = t >> 5, c4 = t & 31;
        int row = row0 + r;
        float4 v = make_float4(0.f, 0.f, 0.f, 0.f);
        if (row < N_NODES) v = ((const float4*)(X + (size_t)row * 128))[c4];
        if (FOLD) {
            int c = c4 * 4;
            v.x = fmaxf(fmaf(v.x, ac[c + 0], ac[128 + c + 0]), 0.f);
            v.y = fmaxf(fmaf(v.y, ac[c + 1], ac[128 + c + 1]), 0.f);
            v.z = fmaxf(fmaf(v.z, ac[c + 2], ac[128 + c + 2]), 0.f);
            v.w = fmaxf(fmaf(v.w, ac[c + 3], ac[128 + c + 3]), 0.f);
        }
        ((float4*)&sX[r][0])[c4] = v;
    }
    __syncthreads();

    const int tx = tid & 15, ty = tid >> 4;  // 16 x 16
    const int c0 = tx * 4, r0 = ty * 4;
    float acc[4][4] = {};
    for (int k = 0; k < 128; k += 4) {
        float4 w0 = *(const float4*)&sW[k + 0][c0];
        float4 w1 = *(const float4*)&sW[k + 1][c0];
        float4 w2 = *(const float4*)&sW[k + 2][c0];
        float4 w3 = *(const float4*)&sW[k + 3][c0];
        #pragma unroll
        for (int r = 0; r < 4; ++r) {
            float4 x = *(const float4*)&sX[r0 + r][k];
            float* a = acc[r];
            a[0] = fmaf(x.x, w0.x, a[0]); a[1] = fmaf(x.x, w0.y, a[1]);
            a[2] = fmaf(x.x, w0.z, a[2]); a[3] = fmaf(x.x, w0.w, a[3]);
            a[0] = fmaf(x.y, w1.x, a[0]); a[1] = fmaf(x.y, w1.y, a[1]);
            a[2] = fmaf(x.y, w1.z, a[2]); a[3] = fmaf(x.y, w1.w, a[3]);
            a[0] = fmaf(x.z, w2.x, a[0]); a[1] = fmaf(x.z, w2.y, a[1]);
            a[2] = fmaf(x.z, w2.z, a[2]); a[3] = fmaf(x.z, w2.w, a[3]);
            a[0] = fmaf(x.w, w3.x, a[0]); a[1] = fmaf(x.w, w3.y, a[1]);
            a[2] = fmaf(x.w, w3.z, a[2]); a[3] = fmaf(x.w, w3.w, a[3]);
        }
    }
    #pragma unroll
    for (int r = 0; r < 4; ++r) {
        int row = row0 + r0 + r;
        int c = bn0 + c0;
        if (row < N_NODES && c + 4 <= LD)
            *(float4*)(Y + (size_t)row * LD + c) = *(float4*)acc[r];
    }
}

// ---------------- aggregation (width 128): out[i] = dinv[i]*sum_e dinv[s]*h[s] + b ----------------
__global__ void agg128_kernel(const float* __restrict__ hin, const float* __restrict__ dinv,
                              const int* __restrict__ offs, const int* __restrict__ csr,
                              const float* __restrict__ bias, float* __restrict__ hout) {
    const int i = blockIdx.x;
    const int f = threadIdx.x;  // 128 threads
    const float di = dinv[i];
    const int e0 = offs[i], e1 = offs[i + 1];
    float a0 = 0.f, a1 = 0.f, a2 = 0.f, a3 = 0.f;
    int e = e0;
    for (; e + 4 <= e1; e += 4) {
        int s0 = csr[e], s1 = csr[e + 1], s2 = csr[e + 2], s3 = csr[e + 3];
        a0 = fmaf(dinv[s0], hin[(size_t)s0 * 128 + f], a0);
        a1 = fmaf(dinv[s1], hin[(size_t)s1 * 128 + f], a1);
        a2 = fmaf(dinv[s2], hin[(size_t)s2 * 128 + f], a2);
        a3 = fmaf(dinv[s3], hin[(size_t)s3 * 128 + f], a3);
    }
    for (; e < e1; ++e) {
        int s = csr[e];
        a0 = fmaf(dinv[s], hin[(size_t)s * 128 + f], a0);
    }
    float acc = (a0 + a1) + (a2 + a3);
    hout[(size_t)i * 128 + f] = fmaf(acc, di, bias[f]);
}

// ---------------- BN statistics ----------------
__global__ void stats_kernel(const float* __restrict__ h, float* __restrict__ stats) {
    const int f = threadIdx.x;  // 128
    float s = 0.f, q = 0.f;
    for (int i = blockIdx.x; i < N_NODES; i += gridDim.x) {
        float v = h[(size_t)i * 128 + f];
        s += v;
        q = fmaf(v, v, q);
    }
    atomicAdd(&stats[f], s);
    atomicAdd(&stats[128 + f], q);
}

__global__ void finalize_kernel(const float* __restrict__ stats, const float* __restrict__ gamma,
                                const float* __restrict__ beta, float* __restrict__ ac) {
    int f = threadIdx.x;  // 128
    float mean = stats[f] * (1.f / N_NODES);
    float var = stats[128 + f] * (1.f / N_NODES) - mean * mean;
    float a = gamma[f] * rsqrtf(var + BN_EPS);
    ac[f] = a;
    ac[128 + f] = fmaf(-mean, a, beta[f]);
}

// ---------------- final aggregation (width 40) + bias + log_softmax ----------------
__global__ void agg_lsm_kernel(const float* __restrict__ hin, const float* __restrict__ dinv,
                               const int* __restrict__ offs, const int* __restrict__ csr,
                               const float* __restrict__ bias, float* __restrict__ out) {
    const int i = blockIdx.x;
    const int f = threadIdx.x;  // 64 threads (one wave); lanes >= 40 idle for features
    const float di = dinv[i];
    const int e0 = offs[i], e1 = offs[i + 1];
    float acc = 0.f;
    if (f < NCLS) {
        float a0 = 0.f, a1 = 0.f;
        int e = e0;
        for (; e + 2 <= e1; e += 2) {
            int s0 = csr[e], s1 = csr[e + 1];
            a0 = fmaf(dinv[s0], hin[(size_t)s0 * NCLS + f], a0);
            a1 = fmaf(dinv[s1], hin[(size_t)s1 * NCLS + f], a1);
        }
        for (; e < e1; ++e) {
            int s = csr[e];
            a0 = fmaf(dinv[s], hin[(size_t)s * NCLS + f], a0);
        }
        acc = fmaf(a0 + a1, di, bias[f]);
    }
    float v = (f < NCLS) ? acc : -INFINITY;
    #pragma unroll
    for (int o = 32; o >= 1; o >>= 1) v = fmaxf(v, __shfl_xor(v, o));
    float ex = (f < NCLS) ? expf(acc - v) : 0.f;
    float s = ex;
    #pragma unroll
    for (int o = 32; o >= 1; o >>= 1) s += __shfl_xor(s, o);
    float lse = v + logf(s);
    if (f < NCLS) out[(size_t)i * NCLS + f] = acc - lse;
}

extern "C" void kernel_launch(void* const* d_in, const int* in_sizes, int n_in,
                              void* d_out, int out_size, void* d_ws, size_t ws_size,
                              hipStream_t stream) {
    const float* x   = (const float*)d_in[0];
    const int*   ei  = (const int*)d_in[1];
    const float* W1  = (const float*)d_in[2];
    const float* b1  = (const float*)d_in[3];
    const float* g1  = (const float*)d_in[4];
    const float* be1 = (const float*)d_in[5];
    const float* W2  = (const float*)d_in[6];
    const float* b2  = (const float*)d_in[7];
    const float* g2  = (const float*)d_in[8];
    const float* be2 = (const float*)d_in[9];
    const float* W3  = (const float*)d_in[10];
    const float* b3  = (const float*)d_in[11];
    float* out = (float*)d_out;

    char* w = (char*)d_ws;
    size_t off = 0;
    auto take = [&](size_t bytes) {
        void* p = w + off;
        off = (off + bytes + 255) & ~(size_t)255;
        return p;
    };
    int*   deg    = (int*)take((size_t)N_NODES * 4);
    float* dinv   = (float*)take((size_t)N_NODES * 4);
    int*   offs   = (int*)take((size_t)(N_NODES + 1) * 4);
    int*   cursor = (int*)take((size_t)N_NODES * 4);
    int*   csr    = (int*)take((size_t)(N_EDGES + N_NODES) * 4);
    int*   bsum   = (int*)take((size_t)SCAN_NB * 4);
    float* stats1 = (float*)take(256 * 4);
    float* stats2 = (float*)take(256 * 4);
    float* ac1    = (float*)take(256 * 4);
    float* ac2    = (float*)take(256 * 4);
    float* bufA   = (float*)take((size_t)N_NODES * 128 * 4);
    float* bufB   = (float*)take((size_t)N_NODES * 128 * 4);

    hipMemsetAsync(deg, 0, (size_t)N_NODES * 4, stream);
    hipMemsetAsync(stats1, 0, 256 * 4, stream);
    hipMemsetAsync(stats2, 0, 256 * 4, stream);

    deg_kernel<<<(N_EDGES + 255) / 256, 256, 0, stream>>>(ei, deg);
    dinv_kernel<<<(N_NODES + 255) / 256, 256, 0, stream>>>(deg, dinv);
    scan1_kernel<<<SCAN_NB, 256, 0, stream>>>(deg, bsum);
    scan2_kernel<<<1, 64, 0, stream>>>(bsum, offs);
    scan3_kernel<<<SCAN_NB, 256, 0, stream>>>(deg, bsum, offs, cursor);
    fill_kernel<<<(N_EDGES + N_NODES + 255) / 256, 256, 0, stream>>>(ei, cursor, csr);

    const int gm = (N_NODES + 63) / 64;  // 1563
    // layer 1
    gemm_kernel<false, 128><<<dim3(gm, 2), 256, 0, stream>>>(x, W1, nullptr, bufA);
    agg128_kernel<<<N_NODES, 128, 0, stream>>>(bufA, dinv, offs, csr, b1, bufB);
    stats_kernel<<<1024, 128, 0, stream>>>(bufB, stats1);
    finalize_kernel<<<1, 128, 0, stream>>>(stats1, g1, be1, ac1);
    // layer 2
    gemm_kernel<true, 128><<<dim3(gm, 2), 256, 0, stream>>>(bufB, W2, ac1, bufA);
    agg128_kernel<<<N_NODES, 128, 0, stream>>>(bufA, dinv, offs, csr, b2, bufB);
    stats_kernel<<<1024, 128, 0, stream>>>(bufB, stats2);
    finalize_kernel<<<1, 128, 0, stream>>>(stats2, g2, be2, ac2);
    // layer 3 (output width 40) -> bufA used as [N x 40]
    gemm_kernel<true, 40><<<dim3(gm, 1), 256, 0, stream>>>(bufB, W3, ac2, bufA);
    agg_lsm_kernel<<<N_NODES, 64, 0, stream>>>(bufA, dinv, offs, csr, b3, out);
}

// Round 2
// 647.937 us; speedup vs baseline: 1.2447x; 1.2447x over previous
//
#include <hip/hip_runtime.h>
#include <math.h>

#define N_NODES 100000
#define N_EDGES 1600000
#define F_INF 128
#define HIDF 128
#define NCLS 40
#define BN_EPS 1e-5f

// ---- bucketed CSR build parameters ----
#define BSPAN 256                    // nodes per bucket
#define NBKT 391                     // ceil(100000/256)
#define GBIN 256                     // phase-A workgroups
#define CHUNK (N_EDGES / GBIN)       // 6250 edges per phase-A WG (exact)
#define ECAP 5120                    // max edges per bucket (mean 4096, sd 64)

// ---------------- Phase A: per-WG bucket binning ----------------
__global__ __launch_bounds__(256) void binA_kernel(const int* __restrict__ ei,
                                                   int2* __restrict__ ebuf,
                                                   int* __restrict__ runstart) {
    __shared__ int hist[NBKT];
    __shared__ int tmp[256];
    const int s = blockIdx.x, tid = threadIdx.x;
    const int e0 = s * CHUNK;

    for (int b = tid; b < NBKT; b += 256) hist[b] = 0;
    __syncthreads();
    for (int j = tid; j < CHUNK; j += 256) {
        int dst = ei[N_EDGES + e0 + j];
        atomicAdd(&hist[dst >> 8], 1);
    }
    __syncthreads();
    // exclusive scan of hist[0..NBKT) via pair-per-thread Hillis-Steele
    int i0 = 2 * tid, i1 = 2 * tid + 1;
    int a = (i0 < NBKT) ? hist[i0] : 0;
    int c = (i1 < NBKT) ? hist[i1] : 0;
    int ps = a + c;
    tmp[tid] = ps;
    __syncthreads();
    for (int o = 1; o < 256; o <<= 1) {
        int t = (tid >= o) ? tmp[tid - o] : 0;
        __syncthreads();
        tmp[tid] += t;
        __syncthreads();
    }
    int excl = tmp[tid] - ps;
    if (i0 < NBKT) hist[i0] = excl;
    if (i1 < NBKT) hist[i1] = excl + a;
    __syncthreads();
    // publish run starts for this WG (column s)
    for (int b = tid; b < NBKT; b += 256) runstart[b * GBIN + s] = hist[b];
    if (tid == 0) runstart[NBKT * GBIN + s] = CHUNK;
    __syncthreads();
    // scatter pairs into this WG's private staging region (L2-local)
    for (int j = tid; j < CHUNK; j += 256) {
        int src = ei[e0 + j];
        int dst = ei[N_EDGES + e0 + j];
        int p = atomicAdd(&hist[dst >> 8], 1);
        ebuf[e0 + p] = make_int2(src, dst);
    }
}

// ---------------- Phase B: column sums of runstart rows ----------------
__global__ void rowsum_kernel(const int* __restrict__ runstart, int* __restrict__ colsum) {
    __shared__ int tmp[256];
    const int b = blockIdx.x;  // 0..NBKT (inclusive row)
    tmp[threadIdx.x] = runstart[b * GBIN + threadIdx.x];
    __syncthreads();
    for (int o = 128; o >= 1; o >>= 1) {
        if (threadIdx.x < o) tmp[threadIdx.x] += tmp[threadIdx.x + o];
        __syncthreads();
    }
    if (threadIdx.x == 0) colsum[b] = tmp[0];
}

// ---------------- Phase C: per-bucket counting sort in LDS ----------------
__global__ __launch_bounds__(256) void binC_kernel(const int2* __restrict__ ebuf,
                                                   const int* __restrict__ runstart,
                                                   const int* __restrict__ colsum,
                                                   int* __restrict__ csr, int* __restrict__ offs,
                                                   float* __restrict__ dinv) {
    __shared__ int srcs[ECAP];
    __shared__ unsigned char dl8[ECAP];
    __shared__ int sorted[ECAP + BSPAN];
    __shared__ int nodecnt[BSPAN];
    __shared__ int cursor[BSPAN];
    __shared__ int tmp[256];
    const int b = blockIdx.x, tid = threadIdx.x;
    const int nb0 = b * BSPAN;
    const int nnod = min(BSPAN, N_NODES - nb0);
    const int base = colsum[b] + nb0;  // csr base: edges before bucket + selfloops before bucket

    // my phase-A segment for this bucket
    int r0 = runstart[b * GBIN + tid];
    int r1 = runstart[(b + 1) * GBIN + tid];
    int len = r1 - r0;
    tmp[tid] = len;
    __syncthreads();
    for (int o = 1; o < 256; o <<= 1) {
        int t = (tid >= o) ? tmp[tid - o] : 0;
        __syncthreads();
        tmp[tid] += t;
        __syncthreads();
    }
    int myoff = tmp[tid] - len;
    int total_e = tmp[255];
    if (total_e > ECAP) total_e = ECAP;  // safety net (statistically unreachable)
    for (int n = tid; n < BSPAN; n += 256) nodecnt[n] = 0;
    __syncthreads();
    // copy my segment into LDS + per-node histogram
    const int2* seg = ebuf + (size_t)tid * CHUNK + r0;
    for (int j = 0; j < len; ++j) {
        int idx = myoff + j;
        if (idx >= ECAP) break;
        int2 p = seg[j];
        srcs[idx] = p.x;
        int dl = p.y - nb0;
        dl8[idx] = (unsigned char)dl;
        atomicAdd(&nodecnt[dl], 1);
    }
    __syncthreads();
    // scan per-node counts (+1 self loop each)
    int cnt = (tid < nnod) ? (nodecnt[tid] + 1) : 0;
    tmp[tid] = cnt;
    __syncthreads();
    for (int o = 1; o < 256; o <<= 1) {
        int t = (tid >= o) ? tmp[tid - o] : 0;
        __syncthreads();
        tmp[tid] += t;
        __syncthreads();
    }
    int noff = tmp[tid] - cnt;
    if (tid < nnod) {
        cursor[tid] = noff + 1;      // slot 0 reserved for self loop
        sorted[noff] = nb0 + tid;    // self loop
        offs[nb0 + tid] = base + noff;
        dinv[nb0 + tid] = rsqrtf((float)(nodecnt[tid] + 1));
    }
    if (b == NBKT - 1 && tid == 0) offs[N_NODES] = N_EDGES + N_NODES;
    __syncthreads();
    // scatter edges into node runs
    for (int idx = tid; idx < total_e; idx += 256) {
        int dl = dl8[idx];
        int p = atomicAdd(&cursor[dl], 1);
        sorted[p] = srcs[idx];
    }
    __syncthreads();
    // coalesced stream-out
    int tot = total_e + nnod;
    for (int idx = tid; idx < tot; idx += 256) csr[base + idx] = sorted[idx];
}

// ---------------- GEMM: Y[M x LD] = foldX(X[M x 128]) @ W[128 x LD] ----------------
template <bool FOLD, int LD>
__global__ __launch_bounds__(256) void gemm_kernel(const float* __restrict__ X,
                                                   const float* __restrict__ Wm,
                                                   const float* __restrict__ ac,
                                                   float* __restrict__ Y) {
    __shared__ float sW[128][64];
    __shared__ float sX[64][128];
    const int tid = threadIdx.x;
    const int row0 = blockIdx.x * 64;
    const int bn0 = blockIdx.y * 64;

    for (int t = tid; t < 128 * 16; t += 256) {
        int k = t >> 4, c4 = (t & 15) * 4;
        int c = bn0 + c4;
        float4 v = make_float4(0.f, 0.f, 0.f, 0.f);
        if (c + 4 <= LD) v = *(const float4*)(Wm + (size_t)k * LD + c);
        *(float4*)&sW[k][c4] = v;
    }
    for (int t = tid; t < 64 * 32; t += 256) {
        int r = t >> 5, c4 = t & 31;
        int row = row0 + r;
        float4 v = make_float4(0.f, 0.f, 0.f, 0.f);
        if (row < N_NODES) v = ((const float4*)(X + (size_t)row * 128))[c4];
        if (FOLD) {
            int c = c4 * 4;
            v.x = fmaxf(fmaf(v.x, ac[c + 0], ac[128 + c + 0]), 0.f);
            v.y = fmaxf(fmaf(v.y, ac[c + 1], ac[128 + c + 1]), 0.f);
            v.z = fmaxf(fmaf(v.z, ac[c + 2], ac[128 + c + 2]), 0.f);
            v.w = fmaxf(fmaf(v.w, ac[c + 3], ac[128 + c + 3]), 0.f);
        }
        ((float4*)&sX[r][0])[c4] = v;
    }
    __syncthreads();

    const int tx = tid & 15, ty = tid >> 4;
    const int c0 = tx * 4, r0 = ty * 4;
    float acc[4][4] = {};
    for (int k = 0; k < 128; k += 4) {
        float4 w0 = *(const float4*)&sW[k + 0][c0];
        float4 w1 = *(const float4*)&sW[k + 1][c0];
        float4 w2 = *(const float4*)&sW[k + 2][c0];
        float4 w3 = *(const float4*)&sW[k + 3][c0];
        #pragma unroll
        for (int r = 0; r < 4; ++r) {
            float4 x = *(const float4*)&sX[r0 + r][k];
            float* a = acc[r];
            a[0] = fmaf(x.x, w0.x, a[0]); a[1] = fmaf(x.x, w0.y, a[1]);
            a[2] = fmaf(x.x, w0.z, a[2]); a[3] = fmaf(x.x, w0.w, a[3]);
            a[0] = fmaf(x.y, w1.x, a[0]); a[1] = fmaf(x.y, w1.y, a[1]);
            a[2] = fmaf(x.y, w1.z, a[2]); a[3] = fmaf(x.y, w1.w, a[3]);
            a[0] = fmaf(x.z, w2.x, a[0]); a[1] = fmaf(x.z, w2.y, a[1]);
            a[2] = fmaf(x.z, w2.z, a[2]); a[3] = fmaf(x.z, w2.w, a[3]);
            a[0] = fmaf(x.w, w3.x, a[0]); a[1] = fmaf(x.w, w3.y, a[1]);
            a[2] = fmaf(x.w, w3.z, a[2]); a[3] = fmaf(x.w, w3.w, a[3]);
        }
    }
    #pragma unroll
    for (int r = 0; r < 4; ++r) {
        int row = row0 + r0 + r;
        int c = bn0 + c0;
        if (row < N_NODES && c + 4 <= LD)
            *(float4*)(Y + (size_t)row * LD + c) = *(float4*)acc[r];
    }
}

// ---------------- aggregation (width 128) ----------------
__global__ void agg128_kernel(const float* __restrict__ hin, const float* __restrict__ dinv,
                              const int* __restrict__ offs, const int* __restrict__ csr,
                              const float* __restrict__ bias, float* __restrict__ hout) {
    const int i = blockIdx.x;
    const int f = threadIdx.x;  // 128 threads
    const float di = dinv[i];
    const int e0 = offs[i], e1 = offs[i + 1];
    float a0 = 0.f, a1 = 0.f, a2 = 0.f, a3 = 0.f;
    int e = e0;
    for (; e + 4 <= e1; e += 4) {
        int s0 = csr[e], s1 = csr[e + 1], s2 = csr[e + 2], s3 = csr[e + 3];
        a0 = fmaf(dinv[s0], hin[(size_t)s0 * 128 + f], a0);
        a1 = fmaf(dinv[s1], hin[(size_t)s1 * 128 + f], a1);
        a2 = fmaf(dinv[s2], hin[(size_t)s2 * 128 + f], a2);
        a3 = fmaf(dinv[s3], hin[(size_t)s3 * 128 + f], a3);
    }
    for (; e < e1; ++e) {
        int s = csr[e];
        a0 = fmaf(dinv[s], hin[(size_t)s * 128 + f], a0);
    }
    float acc = (a0 + a1) + (a2 + a3);
    hout[(size_t)i * 128 + f] = fmaf(acc, di, bias[f]);
}

// ---------------- BN statistics ----------------
__global__ void stats_kernel(const float* __restrict__ h, float* __restrict__ stats) {
    const int f = threadIdx.x;  // 128
    float s = 0.f, q = 0.f;
    for (int i = blockIdx.x; i < N_NODES; i += gridDim.x) {
        float v = h[(size_t)i * 128 + f];
        s += v;
        q = fmaf(v, v, q);
    }
    atomicAdd(&stats[f], s);
    atomicAdd(&stats[128 + f], q);
}

__global__ void finalize_kernel(const float* __restrict__ stats, const float* __restrict__ gamma,
                                const float* __restrict__ beta, float* __restrict__ ac) {
    int f = threadIdx.x;  // 128
    float mean = stats[f] * (1.f / N_NODES);
    float var = stats[128 + f] * (1.f / N_NODES) - mean * mean;
    float a = gamma[f] * rsqrtf(var + BN_EPS);
    ac[f] = a;
    ac[128 + f] = fmaf(-mean, a, beta[f]);
}

// ---------------- final aggregation (width 40) + log_softmax ----------------
__global__ void agg_lsm_kernel(const float* __restrict__ hin, const float* __restrict__ dinv,
                               const int* __restrict__ offs, const int* __restrict__ csr,
                               const float* __restrict__ bias, float* __restrict__ out) {
    const int i = blockIdx.x;
    const int f = threadIdx.x;  // 64 threads
    const float di = dinv[i];
    const int e0 = offs[i], e1 = offs[i + 1];
    float acc = 0.f;
    if (f < NCLS) {
        float a0 = 0.f, a1 = 0.f;
        int e = e0;
        for (; e + 2 <= e1; e += 2) {
            int s0 = csr[e], s1 = csr[e + 1];
            a0 = fmaf(dinv[s0], hin[(size_t)s0 * NCLS + f], a0);
            a1 = fmaf(dinv[s1], hin[(size_t)s1 * NCLS + f], a1);
        }
        for (; e < e1; ++e) {
            int s = csr[e];
            a0 = fmaf(dinv[s], hin[(size_t)s * NCLS + f], a0);
        }
        acc = fmaf(a0 + a1, di, bias[f]);
    }
    float v = (f < NCLS) ? acc : -INFINITY;
    #pragma unroll
    for (int o = 32; o >= 1; o >>= 1) v = fmaxf(v, __shfl_xor(v, o));
    float ex = (f < NCLS) ? expf(acc - v) : 0.f;
    float s = ex;
    #pragma unroll
    for (int o = 32; o >= 1; o >>= 1) s += __shfl_xor(s, o);
    float lse = v + logf(s);
    if (f < NCLS) out[(size_t)i * NCLS + f] = acc - lse;
}

extern "C" void kernel_launch(void* const* d_in, const int* in_sizes, int n_in,
                              void* d_out, int out_size, void* d_ws, size_t ws_size,
                              hipStream_t stream) {
    const float* x   = (const float*)d_in[0];
    const int*   ei  = (const int*)d_in[1];
    const float* W1  = (const float*)d_in[2];
    const float* b1  = (const float*)d_in[3];
    const float* g1  = (const float*)d_in[4];
    const float* be1 = (const float*)d_in[5];
    const float* W2  = (const float*)d_in[6];
    const float* b2  = (const float*)d_in[7];
    const float* g2  = (const float*)d_in[8];
    const float* be2 = (const float*)d_in[9];
    const float* W3  = (const float*)d_in[10];
    const float* b3  = (const float*)d_in[11];
    float* out = (float*)d_out;

    char* w = (char*)d_ws;
    size_t off = 0;
    auto take = [&](size_t bytes) {
        void* p = w + off;
        off = (off + bytes + 255) & ~(size_t)255;
        return p;
    };
    float* dinv   = (float*)take((size_t)N_NODES * 4);
    int*   offs   = (int*)take((size_t)(N_NODES + 1) * 4);
    int*   csr    = (int*)take((size_t)(N_EDGES + N_NODES) * 4);
    int*   colsum = (int*)take((size_t)(NBKT + 1) * 4);
    float* stats1 = (float*)take(256 * 4);
    float* stats2 = (float*)take(256 * 4);
    float* ac1    = (float*)take(256 * 4);
    float* ac2    = (float*)take(256 * 4);
    float* bufA   = (float*)take((size_t)N_NODES * 128 * 4);
    float* bufB   = (float*)take((size_t)N_NODES * 128 * 4);

    // CSR-build staging aliases bufA/bufB (consumed before GEMMs write them)
    int2* ebuf     = (int2*)bufA;   // E * 8B = 12.8 MB
    int*  runstart = (int*)bufB;    // (NBKT+1)*GBIN*4 = 401 KB

    hipMemsetAsync(stats1, 0, 256 * 4, stream);
    hipMemsetAsync(stats2, 0, 256 * 4, stream);

    binA_kernel<<<GBIN, 256, 0, stream>>>(ei, ebuf, runstart);
    rowsum_kernel<<<NBKT + 1, 256, 0, stream>>>(runstart, colsum);
    binC_kernel<<<NBKT, 256, 0, stream>>>(ebuf, runstart, colsum, csr, offs, dinv);

    const int gm = (N_NODES + 63) / 64;  // 1563
    // layer 1
    gemm_kernel<false, 128><<<dim3(gm, 2), 256, 0, stream>>>(x, W1, nullptr, bufA);
    agg128_kernel<<<N_NODES, 128, 0, stream>>>(bufA, dinv, offs, csr, b1, bufB);
    stats_kernel<<<1024, 128, 0, stream>>>(bufB, stats1);
    finalize_kernel<<<1, 128, 0, stream>>>(stats1, g1, be1, ac1);
    // layer 2
    gemm_kernel<true, 128><<<dim3(gm, 2), 256, 0, stream>>>(bufB, W2, ac1, bufA);
    agg128_kernel<<<N_NODES, 128, 0, stream>>>(bufA, dinv, offs, csr, b2, bufB);
    stats_kernel<<<1024, 128, 0, stream>>>(bufB, stats2);
    finalize_kernel<<<1, 128, 0, stream>>>(stats2, g2, be2, ac2);
    // layer 3 (output width 40)
    gemm_kernel<true, 40><<<dim3(gm, 1), 256, 0, stream>>>(bufB, W3, ac2, bufA);
    agg_lsm_kernel<<<N_NODES, 64, 0, stream>>>(bufA, dinv, offs, csr, b3, out);
}

// Round 3
// 485.847 us; speedup vs baseline: 1.6600x; 1.3336x over previous
//
#include <hip/hip_runtime.h>
#include <math.h>

#define N_NODES 100000
#define N_EDGES 1600000
#define NCLS 40
#define BN_EPS 1e-5f

// ---- bucketed CSR build parameters ----
#define BSPAN 256
#define NBKT 391
#define GBIN 256
#define CHUNK (N_EDGES / GBIN)
#define ECAP 5120

typedef unsigned int u32;
typedef unsigned short u16;
typedef __attribute__((ext_vector_type(8))) short bf16x8;
typedef __attribute__((ext_vector_type(4))) float f32x4;

__device__ inline float bl_lo(u32 u) { u32 x = u << 16; return __builtin_bit_cast(float, x); }
__device__ inline float bl_hi(u32 u) { u32 x = u & 0xFFFF0000u; return __builtin_bit_cast(float, x); }
__device__ inline u16 f2bl(float f) {  // RNE
    u32 x = __builtin_bit_cast(u32, f);
    return (u16)((x + 0x7FFFu + ((x >> 16) & 1u)) >> 16);
}
__device__ inline u32 pk2(float lo, float hi) { return (u32)f2bl(lo) | ((u32)f2bl(hi) << 16); }

// ---------------- Phase A: per-WG bucket binning ----------------
__global__ __launch_bounds__(256) void binA_kernel(const int* __restrict__ ei,
                                                   int2* __restrict__ ebuf,
                                                   int* __restrict__ runstart) {
    __shared__ int hist[NBKT];
    __shared__ int tmp[256];
    const int s = blockIdx.x, tid = threadIdx.x;
    const int e0 = s * CHUNK;

    for (int b = tid; b < NBKT; b += 256) hist[b] = 0;
    __syncthreads();
    for (int j = tid; j < CHUNK; j += 256) {
        int dst = ei[N_EDGES + e0 + j];
        atomicAdd(&hist[dst >> 8], 1);
    }
    __syncthreads();
    int i0 = 2 * tid, i1 = 2 * tid + 1;
    int a = (i0 < NBKT) ? hist[i0] : 0;
    int c = (i1 < NBKT) ? hist[i1] : 0;
    int ps = a + c;
    tmp[tid] = ps;
    __syncthreads();
    for (int o = 1; o < 256; o <<= 1) {
        int t = (tid >= o) ? tmp[tid - o] : 0;
        __syncthreads();
        tmp[tid] += t;
        __syncthreads();
    }
    int excl = tmp[tid] - ps;
    if (i0 < NBKT) hist[i0] = excl;
    if (i1 < NBKT) hist[i1] = excl + a;
    __syncthreads();
    for (int b = tid; b < NBKT; b += 256) runstart[b * GBIN + s] = hist[b];
    if (tid == 0) runstart[NBKT * GBIN + s] = CHUNK;
    __syncthreads();
    for (int j = tid; j < CHUNK; j += 256) {
        int src = ei[e0 + j];
        int dst = ei[N_EDGES + e0 + j];
        int p = atomicAdd(&hist[dst >> 8], 1);
        ebuf[e0 + p] = make_int2(src, dst);
    }
}

// ---------------- Phase B ----------------
__global__ void rowsum_kernel(const int* __restrict__ runstart, int* __restrict__ colsum) {
    __shared__ int tmp[256];
    const int b = blockIdx.x;
    tmp[threadIdx.x] = runstart[b * GBIN + threadIdx.x];
    __syncthreads();
    for (int o = 128; o >= 1; o >>= 1) {
        if (threadIdx.x < o) tmp[threadIdx.x] += tmp[threadIdx.x + o];
        __syncthreads();
    }
    if (threadIdx.x == 0) colsum[b] = tmp[0];
}

// ---------------- Phase C: per-bucket counting sort in LDS ----------------
__global__ __launch_bounds__(256) void binC_kernel(const int2* __restrict__ ebuf,
                                                   const int* __restrict__ runstart,
                                                   const int* __restrict__ colsum,
                                                   int* __restrict__ csr, int* __restrict__ offs,
                                                   float* __restrict__ dinv) {
    __shared__ int srcs[ECAP];
    __shared__ unsigned char dl8[ECAP];
    __shared__ int sorted[ECAP + BSPAN];
    __shared__ int nodecnt[BSPAN];
    __shared__ int cursor[BSPAN];
    __shared__ int tmp[256];
    const int b = blockIdx.x, tid = threadIdx.x;
    const int nb0 = b * BSPAN;
    const int nnod = min(BSPAN, N_NODES - nb0);
    const int base = colsum[b] + nb0;

    int r0 = runstart[b * GBIN + tid];
    int r1 = runstart[(b + 1) * GBIN + tid];
    int len = r1 - r0;
    tmp[tid] = len;
    __syncthreads();
    for (int o = 1; o < 256; o <<= 1) {
        int t = (tid >= o) ? tmp[tid - o] : 0;
        __syncthreads();
        tmp[tid] += t;
        __syncthreads();
    }
    int myoff = tmp[tid] - len;
    int total_e = tmp[255];
    if (total_e > ECAP) total_e = ECAP;
    for (int n = tid; n < BSPAN; n += 256) nodecnt[n] = 0;
    __syncthreads();
    const int2* seg = ebuf + (size_t)tid * CHUNK + r0;
    for (int j = 0; j < len; ++j) {
        int idx = myoff + j;
        if (idx >= ECAP) break;
        int2 p = seg[j];
        srcs[idx] = p.x;
        int dl = p.y - nb0;
        dl8[idx] = (unsigned char)dl;
        atomicAdd(&nodecnt[dl], 1);
    }
    __syncthreads();
    int cnt = (tid < nnod) ? (nodecnt[tid] + 1) : 0;
    tmp[tid] = cnt;
    __syncthreads();
    for (int o = 1; o < 256; o <<= 1) {
        int t = (tid >= o) ? tmp[tid - o] : 0;
        __syncthreads();
        tmp[tid] += t;
        __syncthreads();
    }
    int noff = tmp[tid] - cnt;
    if (tid < nnod) {
        cursor[tid] = noff + 1;
        sorted[noff] = nb0 + tid;
        offs[nb0 + tid] = base + noff;
        dinv[nb0 + tid] = rsqrtf((float)(nodecnt[tid] + 1));
    }
    if (b == NBKT - 1 && tid == 0) offs[N_NODES] = N_EDGES + N_NODES;
    __syncthreads();
    for (int idx = tid; idx < total_e; idx += 256) {
        int dl = dl8[idx];
        int p = atomicAdd(&cursor[dl], 1);
        sorted[p] = srcs[idx];
    }
    __syncthreads();
    int tot = total_e + nnod;
    for (int idx = tid; idx < tot; idx += 256) csr[base + idx] = sorted[idx];
}

// ---------------- W prep: transpose + bf16 ----------------
__global__ void prep_w(const float* __restrict__ W1, const float* __restrict__ W2,
                       const float* __restrict__ W3, u16* __restrict__ Wt1,
                       u16* __restrict__ Wt2, u16* __restrict__ Wt3) {
    int b = blockIdx.x, t = threadIdx.x;
    if (b == 0) {
        for (int idx = t; idx < 128 * 128; idx += 256) {
            int c = idx >> 7, k = idx & 127;
            Wt1[idx] = f2bl(W1[k * 128 + c]);
        }
    } else if (b == 1) {
        for (int idx = t; idx < 128 * 128; idx += 256) {
            int c = idx >> 7, k = idx & 127;
            Wt2[idx] = f2bl(W2[k * 128 + c]);
        }
    } else {
        for (int idx = t; idx < 48 * 128; idx += 256) {
            int c = idx >> 7, k = idx & 127;
            Wt3[idx] = (c < NCLS) ? f2bl(W3[k * NCLS + c]) : (u16)0;
        }
    }
}

// ---------------- MFMA GEMM: Y[M x BN] = fold(X[M x 128]) @ W[128 x BN] ----------------
// Wt: [BN][128] bf16 (pre-transposed).  sX/sW XOR-swizzled (chunk ^= row&7).
template <bool FOLD, bool IN_BF16, int BN, bool OUT_BF16>
__global__ __launch_bounds__(256) void mfma_gemm(const void* __restrict__ Xv,
                                                 const u16* __restrict__ Wt,
                                                 const float* __restrict__ ac,
                                                 void* __restrict__ Yv) {
    __shared__ __align__(16) u16 sX[64 * 128];
    __shared__ __align__(16) u16 sW[BN * 128];
    const int tid = threadIdx.x;
    const int row0 = blockIdx.x * 64;

    // stage W (bf16 rows, coalesced) with swizzle
    for (int ci = tid; ci < BN * 16; ci += 256) {
        int n = ci >> 4, ch = ci & 15;
        uint4 v = *(const uint4*)(Wt + n * 128 + ch * 8);
        *(uint4*)&sW[n * 128 + ((ch ^ (n & 7)) * 8)] = v;
    }
    // stage X tile (fold + bf16 convert)
    {
        int r = tid >> 2;
        int gr = row0 + r;
        if (gr >= N_NODES) gr = N_NODES - 1;
        #pragma unroll
        for (int i = 0; i < 4; ++i) {
            int ch = (tid & 3) * 4 + i;
            int k0 = ch * 8;
            float xv[8];
            if (IN_BF16) {
                uint4 v = *((const uint4*)Xv + (size_t)gr * 16 + ch);
                xv[0] = bl_lo(v.x); xv[1] = bl_hi(v.x);
                xv[2] = bl_lo(v.y); xv[3] = bl_hi(v.y);
                xv[4] = bl_lo(v.z); xv[5] = bl_hi(v.z);
                xv[6] = bl_lo(v.w); xv[7] = bl_hi(v.w);
            } else {
                float4 p = *((const float4*)Xv + (size_t)gr * 32 + ch * 2);
                float4 q = *((const float4*)Xv + (size_t)gr * 32 + ch * 2 + 1);
                xv[0] = p.x; xv[1] = p.y; xv[2] = p.z; xv[3] = p.w;
                xv[4] = q.x; xv[5] = q.y; xv[6] = q.z; xv[7] = q.w;
            }
            if (FOLD) {
                #pragma unroll
                for (int j = 0; j < 8; ++j)
                    xv[j] = fmaxf(fmaf(xv[j], ac[k0 + j], ac[128 + k0 + j]), 0.f);
            }
            uint4 w;
            w.x = pk2(xv[0], xv[1]); w.y = pk2(xv[2], xv[3]);
            w.z = pk2(xv[4], xv[5]); w.w = pk2(xv[6], xv[7]);
            *(uint4*)&sX[r * 128 + ((ch ^ (r & 7)) * 8)] = w;
        }
    }
    __syncthreads();

    const int w = tid >> 6, l = tid & 63;
    const int g = l >> 4;
    const int lrow = w * 16 + (l & 15);
    bf16x8 afrag[4];
    #pragma unroll
    for (int kc = 0; kc < 4; ++kc) {
        int ch = kc * 4 + g;
        afrag[kc] = *(const bf16x8*)&sX[lrow * 128 + ((ch ^ (lrow & 7)) * 8)];
    }
    #pragma unroll
    for (int cg = 0; cg < BN / 16; ++cg) {
        const int n = cg * 16 + (l & 15);
        f32x4 acc = {0.f, 0.f, 0.f, 0.f};
        #pragma unroll
        for (int kc = 0; kc < 4; ++kc) {
            int ch = kc * 4 + g;
            bf16x8 bfrag = *(const bf16x8*)&sW[n * 128 + ((ch ^ (n & 7)) * 8)];
            acc = __builtin_amdgcn_mfma_f32_16x16x32_bf16(afrag[kc], bfrag, acc, 0, 0, 0);
        }
        #pragma unroll
        for (int r = 0; r < 4; ++r) {
            int row = row0 + w * 16 + g * 4 + r;
            if (row < N_NODES) {
                if (OUT_BF16) {
                    ((u16*)Yv)[(size_t)row * 128 + n] = f2bl(acc[r]);
                } else {
                    if (n < NCLS) ((float*)Yv)[(size_t)row * NCLS + n] = acc[r];
                }
            }
        }
    }
}

// ---------------- aggregation (128 feats as 64 x u32-pair) ----------------
__global__ __launch_bounds__(64) void agg_kernel(const u32* __restrict__ hin,
                                                 const float* __restrict__ dinv,
                                                 const int* __restrict__ offs,
                                                 const int* __restrict__ csr,
                                                 const float* __restrict__ bias,
                                                 u32* __restrict__ hout) {
    const int i = blockIdx.x;
    const int f = threadIdx.x;  // 64 threads, feats 2f / 2f+1
    const float di = dinv[i];
    const int e0 = offs[i], e1 = offs[i + 1];
    float a0l = 0.f, a0h = 0.f, a1l = 0.f, a1h = 0.f;
    float a2l = 0.f, a2h = 0.f, a3l = 0.f, a3h = 0.f;
    int e = e0;
    for (; e + 4 <= e1; e += 4) {
        int s0 = csr[e], s1 = csr[e + 1], s2 = csr[e + 2], s3 = csr[e + 3];
        float d0 = dinv[s0], d1 = dinv[s1], d2 = dinv[s2], d3 = dinv[s3];
        u32 u0 = hin[(size_t)s0 * 64 + f];
        u32 u1 = hin[(size_t)s1 * 64 + f];
        u32 u2 = hin[(size_t)s2 * 64 + f];
        u32 u3 = hin[(size_t)s3 * 64 + f];
        a0l = fmaf(d0, bl_lo(u0), a0l); a0h = fmaf(d0, bl_hi(u0), a0h);
        a1l = fmaf(d1, bl_lo(u1), a1l); a1h = fmaf(d1, bl_hi(u1), a1h);
        a2l = fmaf(d2, bl_lo(u2), a2l); a2h = fmaf(d2, bl_hi(u2), a2h);
        a3l = fmaf(d3, bl_lo(u3), a3l); a3h = fmaf(d3, bl_hi(u3), a3h);
    }
    for (; e < e1; ++e) {
        int s = csr[e];
        float d = dinv[s];
        u32 u = hin[(size_t)s * 64 + f];
        a0l = fmaf(d, bl_lo(u), a0l); a0h = fmaf(d, bl_hi(u), a0h);
    }
    float rl = fmaf((a0l + a1l) + (a2l + a3l), di, bias[2 * f]);
    float rh = fmaf((a0h + a1h) + (a2h + a3h), di, bias[2 * f + 1]);
    hout[(size_t)i * 64 + f] = pk2(rl, rh);
}

// ---------------- BN statistics (bf16 input) ----------------
__global__ __launch_bounds__(64) void stats_kernel(const u32* __restrict__ h,
                                                   float* __restrict__ stats) {
    const int f = threadIdx.x;  // feats 2f, 2f+1
    float s0 = 0.f, s1 = 0.f, q0 = 0.f, q1 = 0.f;
    for (int i = blockIdx.x; i < N_NODES; i += gridDim.x) {
        u32 u = h[(size_t)i * 64 + f];
        float lo = bl_lo(u), hi = bl_hi(u);
        s0 += lo; s1 += hi;
        q0 = fmaf(lo, lo, q0); q1 = fmaf(hi, hi, q1);
    }
    atomicAdd(&stats[2 * f], s0);
    atomicAdd(&stats[2 * f + 1], s1);
    atomicAdd(&stats[128 + 2 * f], q0);
    atomicAdd(&stats[128 + 2 * f + 1], q1);
}

__global__ void finalize_kernel(const float* __restrict__ stats, const float* __restrict__ gamma,
                                const float* __restrict__ beta, float* __restrict__ ac) {
    int f = threadIdx.x;  // 128
    float mean = stats[f] * (1.f / N_NODES);
    float var = stats[128 + f] * (1.f / N_NODES) - mean * mean;
    float a = gamma[f] * rsqrtf(var + BN_EPS);
    ac[f] = a;
    ac[128 + f] = fmaf(-mean, a, beta[f]);
}

// ---------------- final aggregation (width 40, f32) + log_softmax ----------------
__global__ __launch_bounds__(64) void agg_lsm_kernel(const float* __restrict__ hin,
                                                     const float* __restrict__ dinv,
                                                     const int* __restrict__ offs,
                                                     const int* __restrict__ csr,
                                                     const float* __restrict__ bias,
                                                     float* __restrict__ out) {
    const int i = blockIdx.x;
    const int f = threadIdx.x;  // 64
    const float di = dinv[i];
    const int e0 = offs[i], e1 = offs[i + 1];
    float acc = 0.f;
    if (f < NCLS) {
        float a0 = 0.f, a1 = 0.f;
        int e = e0;
        for (; e + 2 <= e1; e += 2) {
            int s0 = csr[e], s1 = csr[e + 1];
            a0 = fmaf(dinv[s0], hin[(size_t)s0 * NCLS + f], a0);
            a1 = fmaf(dinv[s1], hin[(size_t)s1 * NCLS + f], a1);
        }
        for (; e < e1; ++e) {
            int s = csr[e];
            a0 = fmaf(dinv[s], hin[(size_t)s * NCLS + f], a0);
        }
        acc = fmaf(a0 + a1, di, bias[f]);
    }
    float v = (f < NCLS) ? acc : -INFINITY;
    #pragma unroll
    for (int o = 32; o >= 1; o >>= 1) v = fmaxf(v, __shfl_xor(v, o));
    float ex = (f < NCLS) ? expf(acc - v) : 0.f;
    float s = ex;
    #pragma unroll
    for (int o = 32; o >= 1; o >>= 1) s += __shfl_xor(s, o);
    float lse = v + logf(s);
    if (f < NCLS) out[(size_t)i * NCLS + f] = acc - lse;
}

extern "C" void kernel_launch(void* const* d_in, const int* in_sizes, int n_in,
                              void* d_out, int out_size, void* d_ws, size_t ws_size,
                              hipStream_t stream) {
    const float* x   = (const float*)d_in[0];
    const int*   ei  = (const int*)d_in[1];
    const float* W1  = (const float*)d_in[2];
    const float* b1  = (const float*)d_in[3];
    const float* g1  = (const float*)d_in[4];
    const float* be1 = (const float*)d_in[5];
    const float* W2  = (const float*)d_in[6];
    const float* b2  = (const float*)d_in[7];
    const float* g2  = (const float*)d_in[8];
    const float* be2 = (const float*)d_in[9];
    const float* W3  = (const float*)d_in[10];
    const float* b3  = (const float*)d_in[11];
    float* out = (float*)d_out;

    char* w = (char*)d_ws;
    size_t off = 0;
    auto take = [&](size_t bytes) {
        void* p = w + off;
        off = (off + bytes + 255) & ~(size_t)255;
        return p;
    };
    float* dinv   = (float*)take((size_t)N_NODES * 4);
    int*   offs   = (int*)take((size_t)(N_NODES + 1) * 4);
    int*   csr    = (int*)take((size_t)(N_EDGES + N_NODES) * 4);
    int*   colsum = (int*)take((size_t)(NBKT + 1) * 4);
    float* stats1 = (float*)take(256 * 4);
    float* stats2 = (float*)take(256 * 4);
    float* ac1    = (float*)take(256 * 4);
    float* ac2    = (float*)take(256 * 4);
    u16*   Wt1    = (u16*)take(128 * 128 * 2);
    u16*   Wt2    = (u16*)take(128 * 128 * 2);
    u16*   Wt3    = (u16*)take(48 * 128 * 2);
    u32*   bufA   = (u32*)take((size_t)N_NODES * 64 * 4);   // bf16 [N][128]
    u32*   bufB   = (u32*)take((size_t)N_NODES * 64 * 4);   // bf16 [N][128]

    // CSR-build staging aliases bufA/bufB (consumed before GEMMs write them)
    int2* ebuf     = (int2*)bufA;
    int*  runstart = (int*)bufB;
    float* Y3      = (float*)bufA;  // [N][40] f32, layer-3 output

    hipMemsetAsync(stats1, 0, 256 * 4, stream);
    hipMemsetAsync(stats2, 0, 256 * 4, stream);

    prep_w<<<3, 256, 0, stream>>>(W1, W2, W3, Wt1, Wt2, Wt3);
    binA_kernel<<<GBIN, 256, 0, stream>>>(ei, ebuf, runstart);
    rowsum_kernel<<<NBKT + 1, 256, 0, stream>>>(runstart, colsum);
    binC_kernel<<<NBKT, 256, 0, stream>>>(ebuf, runstart, colsum, csr, offs, dinv);

    const int gm = (N_NODES + 63) / 64;  // 1563
    // layer 1
    mfma_gemm<false, false, 128, true><<<gm, 256, 0, stream>>>(x, Wt1, nullptr, bufA);
    agg_kernel<<<N_NODES, 64, 0, stream>>>(bufA, dinv, offs, csr, b1, bufB);
    stats_kernel<<<1024, 64, 0, stream>>>(bufB, stats1);
    finalize_kernel<<<1, 128, 0, stream>>>(stats1, g1, be1, ac1);
    // layer 2
    mfma_gemm<true, true, 128, true><<<gm, 256, 0, stream>>>(bufB, Wt2, ac1, bufA);
    agg_kernel<<<N_NODES, 64, 0, stream>>>(bufA, dinv, offs, csr, b2, bufB);
    stats_kernel<<<1024, 64, 0, stream>>>(bufB, stats2);
    finalize_kernel<<<1, 128, 0, stream>>>(stats2, g2, be2, ac2);
    // layer 3 (width 40, f32 out)
    mfma_gemm<true, true, 48, false><<<gm, 256, 0, stream>>>(bufB, Wt3, ac2, Y3);
    agg_lsm_kernel<<<N_NODES, 64, 0, stream>>>(Y3, dinv, offs, csr, b3, out);
}

// Round 4
// 480.189 us; speedup vs baseline: 1.6796x; 1.0118x over previous
//
#include <hip/hip_runtime.h>
#include <math.h>

#define N_NODES 100000
#define N_EDGES 1600000
#define NCLS 40
#define BN_EPS 1e-5f

// ---- bucketed CSR build parameters ----
#define BSPAN 256
#define NBKT 391
#define GBIN 256
#define CHUNK (N_EDGES / GBIN)
#define ECAP 5120

typedef unsigned int u32;
typedef unsigned short u16;
typedef __attribute__((ext_vector_type(8))) short bf16x8;
typedef __attribute__((ext_vector_type(4))) float f32x4;

__device__ inline float bl_lo(u32 u) { u32 x = u << 16; return __builtin_bit_cast(float, x); }
__device__ inline float bl_hi(u32 u) { u32 x = u & 0xFFFF0000u; return __builtin_bit_cast(float, x); }
__device__ inline u16 f2bl(float f) {  // RNE
    u32 x = __builtin_bit_cast(u32, f);
    return (u16)((x + 0x7FFFu + ((x >> 16) & 1u)) >> 16);
}
__device__ inline u32 pk2(float lo, float hi) { return (u32)f2bl(lo) | ((u32)f2bl(hi) << 16); }

// ---------------- Phase A: per-WG bucket binning ----------------
__global__ __launch_bounds__(256) void binA_kernel(const int* __restrict__ ei,
                                                   int2* __restrict__ ebuf,
                                                   int* __restrict__ runstart) {
    __shared__ int hist[NBKT];
    __shared__ int tmp[256];
    const int s = blockIdx.x, tid = threadIdx.x;
    const int e0 = s * CHUNK;

    for (int b = tid; b < NBKT; b += 256) hist[b] = 0;
    __syncthreads();
    for (int j = tid; j < CHUNK; j += 256) {
        int dst = ei[N_EDGES + e0 + j];
        atomicAdd(&hist[dst >> 8], 1);
    }
    __syncthreads();
    int i0 = 2 * tid, i1 = 2 * tid + 1;
    int a = (i0 < NBKT) ? hist[i0] : 0;
    int c = (i1 < NBKT) ? hist[i1] : 0;
    int ps = a + c;
    tmp[tid] = ps;
    __syncthreads();
    for (int o = 1; o < 256; o <<= 1) {
        int t = (tid >= o) ? tmp[tid - o] : 0;
        __syncthreads();
        tmp[tid] += t;
        __syncthreads();
    }
    int excl = tmp[tid] - ps;
    if (i0 < NBKT) hist[i0] = excl;
    if (i1 < NBKT) hist[i1] = excl + a;
    __syncthreads();
    for (int b = tid; b < NBKT; b += 256) runstart[b * GBIN + s] = hist[b];
    if (tid == 0) runstart[NBKT * GBIN + s] = CHUNK;
    __syncthreads();
    for (int j = tid; j < CHUNK; j += 256) {
        int src = ei[e0 + j];
        int dst = ei[N_EDGES + e0 + j];
        int p = atomicAdd(&hist[dst >> 8], 1);
        ebuf[e0 + p] = make_int2(src, dst);
    }
}

// ---------------- Phase C: per-bucket counting sort in LDS (rowsum folded in) ----------------
__global__ __launch_bounds__(256) void binC_kernel(const int2* __restrict__ ebuf,
                                                   const int* __restrict__ runstart,
                                                   int* __restrict__ csr, int* __restrict__ offs,
                                                   float* __restrict__ dinv) {
    __shared__ int srcs[ECAP];
    __shared__ unsigned char dl8[ECAP];
    __shared__ int sorted[ECAP + BSPAN];
    __shared__ int nodecnt[BSPAN];
    __shared__ int cursor[BSPAN];
    __shared__ int tmp[256];
    __shared__ int sbase;
    const int b = blockIdx.x, tid = threadIdx.x;
    const int nb0 = b * BSPAN;
    const int nnod = min(BSPAN, N_NODES - nb0);

    int r0 = runstart[b * GBIN + tid];
    int r1 = runstart[(b + 1) * GBIN + tid];
    int len = r1 - r0;

    // global edge-prefix for this bucket: sum_s r0  (edges with bucket < b in every chunk)
    tmp[tid] = r0;
    __syncthreads();
    for (int o = 128; o >= 1; o >>= 1) {
        if (tid < o) tmp[tid] += tmp[tid + o];
        __syncthreads();
    }
    if (tid == 0) sbase = tmp[0] + nb0;  // + self loops before bucket
    __syncthreads();
    const int base = sbase;

    tmp[tid] = len;
    __syncthreads();
    for (int o = 1; o < 256; o <<= 1) {
        int t = (tid >= o) ? tmp[tid - o] : 0;
        __syncthreads();
        tmp[tid] += t;
        __syncthreads();
    }
    int myoff = tmp[tid] - len;
    int total_e = tmp[255];
    if (total_e > ECAP) total_e = ECAP;
    for (int n = tid; n < BSPAN; n += 256) nodecnt[n] = 0;
    __syncthreads();
    const int2* seg = ebuf + (size_t)tid * CHUNK + r0;
    for (int j = 0; j < len; ++j) {
        int idx = myoff + j;
        if (idx >= ECAP) break;
        int2 p = seg[j];
        srcs[idx] = p.x;
        int dl = p.y - nb0;
        dl8[idx] = (unsigned char)dl;
        atomicAdd(&nodecnt[dl], 1);
    }
    __syncthreads();
    int cnt = (tid < nnod) ? (nodecnt[tid] + 1) : 0;
    tmp[tid] = cnt;
    __syncthreads();
    for (int o = 1; o < 256; o <<= 1) {
        int t = (tid >= o) ? tmp[tid - o] : 0;
        __syncthreads();
        tmp[tid] += t;
        __syncthreads();
    }
    int noff = tmp[tid] - cnt;
    if (tid < nnod) {
        cursor[tid] = noff + 1;
        sorted[noff] = nb0 + tid;
        offs[nb0 + tid] = base + noff;
        dinv[nb0 + tid] = rsqrtf((float)(nodecnt[tid] + 1));
    }
    if (b == NBKT - 1 && tid == 0) offs[N_NODES] = N_EDGES + N_NODES;
    __syncthreads();
    for (int idx = tid; idx < total_e; idx += 256) {
        int dl = dl8[idx];
        int p = atomicAdd(&cursor[dl], 1);
        sorted[p] = srcs[idx];
    }
    __syncthreads();
    int tot = total_e + nnod;
    for (int idx = tid; idx < tot; idx += 256) csr[base + idx] = sorted[idx];
}

// ---------------- W prep: transpose + bf16 ----------------
__global__ void prep_w(const float* __restrict__ W1, const float* __restrict__ W2,
                       const float* __restrict__ W3, u16* __restrict__ Wt1,
                       u16* __restrict__ Wt2, u16* __restrict__ Wt3) {
    int b = blockIdx.x, t = threadIdx.x;
    if (b == 0) {
        for (int idx = t; idx < 128 * 128; idx += 256) {
            int c = idx >> 7, k = idx & 127;
            Wt1[idx] = f2bl(W1[k * 128 + c]);
        }
    } else if (b == 1) {
        for (int idx = t; idx < 128 * 128; idx += 256) {
            int c = idx >> 7, k = idx & 127;
            Wt2[idx] = f2bl(W2[k * 128 + c]);
        }
    } else {
        for (int idx = t; idx < 48 * 128; idx += 256) {
            int c = idx >> 7, k = idx & 127;
            Wt3[idx] = (c < NCLS) ? f2bl(W3[k * NCLS + c]) : (u16)0;
        }
    }
}

// ---------------- MFMA GEMM: Y = fold(X[M x 128]) @ W[128 x BN] ----------------
// OUTMODE: 0 = bf16 [N][128]; 1 = bf16 [N][40] (n<40 only)
template <bool FOLD, bool IN_BF16, int BN, int OUTMODE>
__global__ __launch_bounds__(256) void mfma_gemm(const void* __restrict__ Xv,
                                                 const u16* __restrict__ Wt,
                                                 const float* __restrict__ ac,
                                                 void* __restrict__ Yv) {
    __shared__ __align__(16) u16 sX[64 * 128];
    __shared__ __align__(16) u16 sW[BN * 128];
    const int tid = threadIdx.x;
    const int row0 = blockIdx.x * 64;

    for (int ci = tid; ci < BN * 16; ci += 256) {
        int n = ci >> 4, ch = ci & 15;
        uint4 v = *(const uint4*)(Wt + n * 128 + ch * 8);
        *(uint4*)&sW[n * 128 + ((ch ^ (n & 7)) * 8)] = v;
    }
    {
        int r = tid >> 2;
        int gr = row0 + r;
        if (gr >= N_NODES) gr = N_NODES - 1;
        #pragma unroll
        for (int i = 0; i < 4; ++i) {
            int ch = (tid & 3) * 4 + i;
            int k0 = ch * 8;
            float xv[8];
            if (IN_BF16) {
                uint4 v = *((const uint4*)Xv + (size_t)gr * 16 + ch);
                xv[0] = bl_lo(v.x); xv[1] = bl_hi(v.x);
                xv[2] = bl_lo(v.y); xv[3] = bl_hi(v.y);
                xv[4] = bl_lo(v.z); xv[5] = bl_hi(v.z);
                xv[6] = bl_lo(v.w); xv[7] = bl_hi(v.w);
            } else {
                float4 p = *((const float4*)Xv + (size_t)gr * 32 + ch * 2);
                float4 q = *((const float4*)Xv + (size_t)gr * 32 + ch * 2 + 1);
                xv[0] = p.x; xv[1] = p.y; xv[2] = p.z; xv[3] = p.w;
                xv[4] = q.x; xv[5] = q.y; xv[6] = q.z; xv[7] = q.w;
            }
            if (FOLD) {
                #pragma unroll
                for (int j = 0; j < 8; ++j)
                    xv[j] = fmaxf(fmaf(xv[j], ac[k0 + j], ac[128 + k0 + j]), 0.f);
            }
            uint4 w;
            w.x = pk2(xv[0], xv[1]); w.y = pk2(xv[2], xv[3]);
            w.z = pk2(xv[4], xv[5]); w.w = pk2(xv[6], xv[7]);
            *(uint4*)&sX[r * 128 + ((ch ^ (r & 7)) * 8)] = w;
        }
    }
    __syncthreads();

    const int w = tid >> 6, l = tid & 63;
    const int g = l >> 4;
    const int lrow = w * 16 + (l & 15);
    bf16x8 afrag[4];
    #pragma unroll
    for (int kc = 0; kc < 4; ++kc) {
        int ch = kc * 4 + g;
        afrag[kc] = *(const bf16x8*)&sX[lrow * 128 + ((ch ^ (lrow & 7)) * 8)];
    }
    #pragma unroll
    for (int cg = 0; cg < BN / 16; ++cg) {
        const int n = cg * 16 + (l & 15);
        f32x4 acc = {0.f, 0.f, 0.f, 0.f};
        #pragma unroll
        for (int kc = 0; kc < 4; ++kc) {
            int ch = kc * 4 + g;
            bf16x8 bfrag = *(const bf16x8*)&sW[n * 128 + ((ch ^ (n & 7)) * 8)];
            acc = __builtin_amdgcn_mfma_f32_16x16x32_bf16(afrag[kc], bfrag, acc, 0, 0, 0);
        }
        #pragma unroll
        for (int r = 0; r < 4; ++r) {
            int row = row0 + w * 16 + g * 4 + r;
            if (row < N_NODES) {
                if (OUTMODE == 0) {
                    ((u16*)Yv)[(size_t)row * 128 + n] = f2bl(acc[r]);
                } else {
                    if (n < NCLS) ((u16*)Yv)[(size_t)row * NCLS + n] = f2bl(acc[r]);
                }
            }
        }
    }
}

// ---------------- aggregation (128 feats as 64 x u32-pair) ----------------
__global__ __launch_bounds__(64) void agg_kernel(const u32* __restrict__ hin,
                                                 const float* __restrict__ dinv,
                                                 const int* __restrict__ offs,
                                                 const int* __restrict__ csr,
                                                 const float* __restrict__ bias,
                                                 u32* __restrict__ hout) {
    const int i = blockIdx.x;
    const int f = threadIdx.x;
    const float di = dinv[i];
    const int e0 = offs[i], e1 = offs[i + 1];
    float a0l = 0.f, a0h = 0.f, a1l = 0.f, a1h = 0.f;
    float a2l = 0.f, a2h = 0.f, a3l = 0.f, a3h = 0.f;
    int e = e0;
    for (; e + 4 <= e1; e += 4) {
        int s0 = csr[e], s1 = csr[e + 1], s2 = csr[e + 2], s3 = csr[e + 3];
        float d0 = dinv[s0], d1 = dinv[s1], d2 = dinv[s2], d3 = dinv[s3];
        u32 u0 = hin[(size_t)s0 * 64 + f];
        u32 u1 = hin[(size_t)s1 * 64 + f];
        u32 u2 = hin[(size_t)s2 * 64 + f];
        u32 u3 = hin[(size_t)s3 * 64 + f];
        a0l = fmaf(d0, bl_lo(u0), a0l); a0h = fmaf(d0, bl_hi(u0), a0h);
        a1l = fmaf(d1, bl_lo(u1), a1l); a1h = fmaf(d1, bl_hi(u1), a1h);
        a2l = fmaf(d2, bl_lo(u2), a2l); a2h = fmaf(d2, bl_hi(u2), a2h);
        a3l = fmaf(d3, bl_lo(u3), a3l); a3h = fmaf(d3, bl_hi(u3), a3h);
    }
    for (; e < e1; ++e) {
        int s = csr[e];
        float d = dinv[s];
        u32 u = hin[(size_t)s * 64 + f];
        a0l = fmaf(d, bl_lo(u), a0l); a0h = fmaf(d, bl_hi(u), a0h);
    }
    float rl = fmaf((a0l + a1l) + (a2l + a3l), di, bias[2 * f]);
    float rh = fmaf((a0h + a1h) + (a2h + a3h), di, bias[2 * f + 1]);
    hout[(size_t)i * 64 + f] = pk2(rl, rh);
}

// ---------------- BN statistics (bf16 input) ----------------
__global__ __launch_bounds__(64) void stats_kernel(const u32* __restrict__ h,
                                                   float* __restrict__ stats) {
    const int f = threadIdx.x;
    float s0 = 0.f, s1 = 0.f, q0 = 0.f, q1 = 0.f;
    for (int i = blockIdx.x; i < N_NODES; i += gridDim.x) {
        u32 u = h[(size_t)i * 64 + f];
        float lo = bl_lo(u), hi = bl_hi(u);
        s0 += lo; s1 += hi;
        q0 = fmaf(lo, lo, q0); q1 = fmaf(hi, hi, q1);
    }
    atomicAdd(&stats[2 * f], s0);
    atomicAdd(&stats[2 * f + 1], s1);
    atomicAdd(&stats[128 + 2 * f], q0);
    atomicAdd(&stats[128 + 2 * f + 1], q1);
}

__global__ void finalize_kernel(const float* __restrict__ stats, const float* __restrict__ gamma,
                                const float* __restrict__ beta, float* __restrict__ ac) {
    int f = threadIdx.x;
    float mean = stats[f] * (1.f / N_NODES);
    float var = stats[128 + f] * (1.f / N_NODES) - mean * mean;
    float a = gamma[f] * rsqrtf(var + BN_EPS);
    ac[f] = a;
    ac[128 + f] = fmaf(-mean, a, beta[f]);
}

// ---------------- final aggregation (bf16 [N][40]) + log_softmax ----------------
// lane = es*20 + cp  (es: edge slot 0..2, cp: class pair 0..19); lanes 60-63 idle
__global__ __launch_bounds__(64) void agg_lsm_kernel(const u32* __restrict__ hin,
                                                     const float* __restrict__ dinv,
                                                     const int* __restrict__ offs,
                                                     const int* __restrict__ csr,
                                                     const float* __restrict__ bias,
                                                     float* __restrict__ out) {
    const int i = blockIdx.x;
    const int lane = threadIdx.x;
    const int es = lane / 20, cp = lane % 20;
    const bool act = es < 3;
    const float di = dinv[i];
    const int e0 = offs[i], e1 = offs[i + 1];
    float al = 0.f, ah = 0.f, bl2 = 0.f, bh2 = 0.f;
    for (int e = e0; e < e1; e += 6) {
        int ee0 = e + es, ee1 = e + 3 + es;
        if (act && ee0 < e1) {
            int s = csr[ee0];
            float d = dinv[s];
            u32 u = hin[(size_t)s * 20 + cp];
            al = fmaf(d, bl_lo(u), al);
            ah = fmaf(d, bl_hi(u), ah);
        }
        if (act && ee1 < e1) {
            int s = csr[ee1];
            float d = dinv[s];
            u32 u = hin[(size_t)s * 20 + cp];
            bl2 = fmaf(d, bl_lo(u), bl2);
            bh2 = fmaf(d, bl_hi(u), bh2);
        }
    }
    al += bl2;
    ah += bh2;
    // reduce the 3 edge-slot groups down to lanes 0..19
    float al1 = __shfl(al, cp + 20), al2 = __shfl(al, cp + 40);
    float ah1 = __shfl(ah, cp + 20), ah2 = __shfl(ah, cp + 40);
    float lo = fmaf(al + al1 + al2, di, bias[2 * cp]);
    float hi = fmaf(ah + ah1 + ah2, di, bias[2 * cp + 1]);
    // log-softmax over 40 values held as lanes 0..19 x {lo,hi}
    float m = (lane < 20) ? fmaxf(lo, hi) : -INFINITY;
    #pragma unroll
    for (int o = 32; o >= 1; o >>= 1) m = fmaxf(m, __shfl_xor(m, o));
    float ex = (lane < 20) ? (__expf(lo - m) + __expf(hi - m)) : 0.f;
    float s = ex;
    #pragma unroll
    for (int o = 32; o >= 1; o >>= 1) s += __shfl_xor(s, o);
    float lse = m + __logf(s);
    if (lane < 20) {
        float2 r = make_float2(lo - lse, hi - lse);
        *((float2*)out + (size_t)i * 20 + cp) = r;
    }
}

extern "C" void kernel_launch(void* const* d_in, const int* in_sizes, int n_in,
                              void* d_out, int out_size, void* d_ws, size_t ws_size,
                              hipStream_t stream) {
    const float* x   = (const float*)d_in[0];
    const int*   ei  = (const int*)d_in[1];
    const float* W1  = (const float*)d_in[2];
    const float* b1  = (const float*)d_in[3];
    const float* g1  = (const float*)d_in[4];
    const float* be1 = (const float*)d_in[5];
    const float* W2  = (const float*)d_in[6];
    const float* b2  = (const float*)d_in[7];
    const float* g2  = (const float*)d_in[8];
    const float* be2 = (const float*)d_in[9];
    const float* W3  = (const float*)d_in[10];
    const float* b3  = (const float*)d_in[11];
    float* out = (float*)d_out;

    char* w = (char*)d_ws;
    size_t off = 0;
    auto take = [&](size_t bytes) {
        void* p = w + off;
        off = (off + bytes + 255) & ~(size_t)255;
        return p;
    };
    float* dinv   = (float*)take((size_t)N_NODES * 4);
    int*   offs   = (int*)take((size_t)(N_NODES + 1) * 4);
    int*   csr    = (int*)take((size_t)(N_EDGES + N_NODES) * 4);
    float* stats1 = (float*)take(256 * 4);
    float* stats2 = (float*)take(256 * 4);
    float* ac1    = (float*)take(256 * 4);
    float* ac2    = (float*)take(256 * 4);
    u16*   Wt1    = (u16*)take(128 * 128 * 2);
    u16*   Wt2    = (u16*)take(128 * 128 * 2);
    u16*   Wt3    = (u16*)take(48 * 128 * 2);
    u32*   bufA   = (u32*)take((size_t)N_NODES * 64 * 4);
    u32*   bufB   = (u32*)take((size_t)N_NODES * 64 * 4);

    int2* ebuf     = (int2*)bufA;
    int*  runstart = (int*)bufB;
    u32*  Y3       = (u32*)bufA;  // bf16 [N][40] layer-3 logits

    hipMemsetAsync(stats1, 0, 256 * 4, stream);
    hipMemsetAsync(stats2, 0, 256 * 4, stream);

    prep_w<<<3, 256, 0, stream>>>(W1, W2, W3, Wt1, Wt2, Wt3);
    binA_kernel<<<GBIN, 256, 0, stream>>>(ei, ebuf, runstart);
    binC_kernel<<<NBKT, 256, 0, stream>>>(ebuf, runstart, csr, offs, dinv);

    const int gm = (N_NODES + 63) / 64;  // 1563
    // layer 1
    mfma_gemm<false, false, 128, 0><<<gm, 256, 0, stream>>>(x, Wt1, nullptr, bufA);
    agg_kernel<<<N_NODES, 64, 0, stream>>>(bufA, dinv, offs, csr, b1, bufB);
    stats_kernel<<<1024, 64, 0, stream>>>(bufB, stats1);
    finalize_kernel<<<1, 128, 0, stream>>>(stats1, g1, be1, ac1);
    // layer 2
    mfma_gemm<true, true, 128, 0><<<gm, 256, 0, stream>>>(bufB, Wt2, ac1, bufA);
    agg_kernel<<<N_NODES, 64, 0, stream>>>(bufA, dinv, offs, csr, b2, bufB);
    stats_kernel<<<1024, 64, 0, stream>>>(bufB, stats2);
    finalize_kernel<<<1, 128, 0, stream>>>(stats2, g2, be2, ac2);
    // layer 3 (width 40, bf16 out)
    mfma_gemm<true, true, 48, 1><<<gm, 256, 0, stream>>>(bufB, Wt3, ac2, Y3);
    agg_lsm_kernel<<<N_NODES, 64, 0, stream>>>(Y3, dinv, offs, csr, b3, out);
}

// Round 5
// 367.353 us; speedup vs baseline: 2.1954x; 1.3072x over previous
//
#include <hip/hip_runtime.h>
#include <math.h>

#define N_NODES 100000
#define N_EDGES 1600000
#define NCLS 40
#define BN_EPS 1e-5f

// ---- bucketed CSR build parameters ----
#define BSPAN 256
#define NBKT 391
#define GBIN 256
#define CHUNK (N_EDGES / GBIN)
#define ECAP 5120

typedef unsigned int u32;
typedef unsigned short u16;
typedef __attribute__((ext_vector_type(8))) short bf16x8;
typedef __attribute__((ext_vector_type(4))) float f32x4;

__device__ inline float bl_lo(u32 u) { u32 x = u << 16; return __builtin_bit_cast(float, x); }
__device__ inline float bl_hi(u32 u) { u32 x = u & 0xFFFF0000u; return __builtin_bit_cast(float, x); }
__device__ inline u16 f2bl(float f) {  // RNE
    u32 x = __builtin_bit_cast(u32, f);
    return (u16)((x + 0x7FFFu + ((x >> 16) & 1u)) >> 16);
}
__device__ inline u32 pk2(float lo, float hi) { return (u32)f2bl(lo) | ((u32)f2bl(hi) << 16); }

// ---------------- Phase A: per-WG bucket binning ----------------
__global__ __launch_bounds__(256) void binA_kernel(const int* __restrict__ ei,
                                                   int2* __restrict__ ebuf,
                                                   int* __restrict__ runstart) {
    __shared__ int hist[NBKT];
    __shared__ int tmp[256];
    const int s = blockIdx.x, tid = threadIdx.x;
    const int e0 = s * CHUNK;

    for (int b = tid; b < NBKT; b += 256) hist[b] = 0;
    __syncthreads();
    for (int j = tid; j < CHUNK; j += 256) {
        int dst = ei[N_EDGES + e0 + j];
        atomicAdd(&hist[dst >> 8], 1);
    }
    __syncthreads();
    int i0 = 2 * tid, i1 = 2 * tid + 1;
    int a = (i0 < NBKT) ? hist[i0] : 0;
    int c = (i1 < NBKT) ? hist[i1] : 0;
    int ps = a + c;
    tmp[tid] = ps;
    __syncthreads();
    for (int o = 1; o < 256; o <<= 1) {
        int t = (tid >= o) ? tmp[tid - o] : 0;
        __syncthreads();
        tmp[tid] += t;
        __syncthreads();
    }
    int excl = tmp[tid] - ps;
    if (i0 < NBKT) hist[i0] = excl;
    if (i1 < NBKT) hist[i1] = excl + a;
    __syncthreads();
    for (int b = tid; b < NBKT; b += 256) runstart[b * GBIN + s] = hist[b];
    if (tid == 0) runstart[NBKT * GBIN + s] = CHUNK;
    __syncthreads();
    for (int j = tid; j < CHUNK; j += 256) {
        int src = ei[e0 + j];
        int dst = ei[N_EDGES + e0 + j];
        int p = atomicAdd(&hist[dst >> 8], 1);
        ebuf[e0 + p] = make_int2(src, dst);
    }
}

// ---------------- Phase C: per-bucket counting sort in LDS ----------------
__global__ __launch_bounds__(256) void binC_kernel(const int2* __restrict__ ebuf,
                                                   const int* __restrict__ runstart,
                                                   int* __restrict__ csr, int* __restrict__ offs,
                                                   float* __restrict__ dinv) {
    __shared__ int srcs[ECAP];
    __shared__ unsigned char dl8[ECAP];
    __shared__ int sorted[ECAP + BSPAN];
    __shared__ int nodecnt[BSPAN];
    __shared__ int cursor[BSPAN];
    __shared__ int tmp[256];
    __shared__ int sbase;
    const int b = blockIdx.x, tid = threadIdx.x;
    const int nb0 = b * BSPAN;
    const int nnod = min(BSPAN, N_NODES - nb0);

    int r0 = runstart[b * GBIN + tid];
    int r1 = runstart[(b + 1) * GBIN + tid];
    int len = r1 - r0;

    tmp[tid] = r0;
    __syncthreads();
    for (int o = 128; o >= 1; o >>= 1) {
        if (tid < o) tmp[tid] += tmp[tid + o];
        __syncthreads();
    }
    if (tid == 0) sbase = tmp[0] + nb0;
    __syncthreads();
    const int base = sbase;

    tmp[tid] = len;
    __syncthreads();
    for (int o = 1; o < 256; o <<= 1) {
        int t = (tid >= o) ? tmp[tid - o] : 0;
        __syncthreads();
        tmp[tid] += t;
        __syncthreads();
    }
    int myoff = tmp[tid] - len;
    int total_e = tmp[255];
    if (total_e > ECAP) total_e = ECAP;
    for (int n = tid; n < BSPAN; n += 256) nodecnt[n] = 0;
    __syncthreads();
    const int2* seg = ebuf + (size_t)tid * CHUNK + r0;
    for (int j = 0; j < len; ++j) {
        int idx = myoff + j;
        if (idx >= ECAP) break;
        int2 p = seg[j];
        srcs[idx] = p.x;
        int dl = p.y - nb0;
        dl8[idx] = (unsigned char)dl;
        atomicAdd(&nodecnt[dl], 1);
    }
    __syncthreads();
    int cnt = (tid < nnod) ? (nodecnt[tid] + 1) : 0;
    tmp[tid] = cnt;
    __syncthreads();
    for (int o = 1; o < 256; o <<= 1) {
        int t = (tid >= o) ? tmp[tid - o] : 0;
        __syncthreads();
        tmp[tid] += t;
        __syncthreads();
    }
    int noff = tmp[tid] - cnt;
    if (tid < nnod) {
        cursor[tid] = noff + 1;
        sorted[noff] = nb0 + tid;
        offs[nb0 + tid] = base + noff;
        dinv[nb0 + tid] = rsqrtf((float)(nodecnt[tid] + 1));
    }
    if (b == NBKT - 1 && tid == 0) offs[N_NODES] = N_EDGES + N_NODES;
    __syncthreads();
    for (int idx = tid; idx < total_e; idx += 256) {
        int dl = dl8[idx];
        int p = atomicAdd(&cursor[dl], 1);
        sorted[p] = srcs[idx];
    }
    __syncthreads();
    int tot = total_e + nnod;
    for (int idx = tid; idx < tot; idx += 256) csr[base + idx] = sorted[idx];
}

// ---------------- W prep: transpose + bf16 ----------------
__global__ void prep_w(const float* __restrict__ W1, const float* __restrict__ W2,
                       const float* __restrict__ W3, u16* __restrict__ Wt1,
                       u16* __restrict__ Wt2, u16* __restrict__ Wt3) {
    int b = blockIdx.x, t = threadIdx.x;
    if (b == 0) {
        for (int idx = t; idx < 128 * 128; idx += 256) {
            int c = idx >> 7, k = idx & 127;
            Wt1[idx] = f2bl(W1[k * 128 + c]);
        }
    } else if (b == 1) {
        for (int idx = t; idx < 128 * 128; idx += 256) {
            int c = idx >> 7, k = idx & 127;
            Wt2[idx] = f2bl(W2[k * 128 + c]);
        }
    } else {
        for (int idx = t; idx < 48 * 128; idx += 256) {
            int c = idx >> 7, k = idx & 127;
            Wt3[idx] = (c < NCLS) ? f2bl(W3[k * NCLS + c]) : (u16)0;
        }
    }
}

// ---------------- MFMA GEMM: Y = fold(X[M x 128]) @ W[128 x BN] ----------------
template <bool FOLD, bool IN_BF16, int BN, int OUTMODE>
__global__ __launch_bounds__(256) void mfma_gemm(const void* __restrict__ Xv,
                                                 const u16* __restrict__ Wt,
                                                 const float* __restrict__ ac,
                                                 void* __restrict__ Yv) {
    __shared__ __align__(16) u16 sX[64 * 128];
    __shared__ __align__(16) u16 sW[BN * 128];
    const int tid = threadIdx.x;
    const int row0 = blockIdx.x * 64;

    for (int ci = tid; ci < BN * 16; ci += 256) {
        int n = ci >> 4, ch = ci & 15;
        uint4 v = *(const uint4*)(Wt + n * 128 + ch * 8);
        *(uint4*)&sW[n * 128 + ((ch ^ (n & 7)) * 8)] = v;
    }
    {
        int r = tid >> 2;
        int gr = row0 + r;
        if (gr >= N_NODES) gr = N_NODES - 1;
        #pragma unroll
        for (int i = 0; i < 4; ++i) {
            int ch = (tid & 3) * 4 + i;
            int k0 = ch * 8;
            float xv[8];
            if (IN_BF16) {
                uint4 v = *((const uint4*)Xv + (size_t)gr * 16 + ch);
                xv[0] = bl_lo(v.x); xv[1] = bl_hi(v.x);
                xv[2] = bl_lo(v.y); xv[3] = bl_hi(v.y);
                xv[4] = bl_lo(v.z); xv[5] = bl_hi(v.z);
                xv[6] = bl_lo(v.w); xv[7] = bl_hi(v.w);
            } else {
                float4 p = *((const float4*)Xv + (size_t)gr * 32 + ch * 2);
                float4 q = *((const float4*)Xv + (size_t)gr * 32 + ch * 2 + 1);
                xv[0] = p.x; xv[1] = p.y; xv[2] = p.z; xv[3] = p.w;
                xv[4] = q.x; xv[5] = q.y; xv[6] = q.z; xv[7] = q.w;
            }
            if (FOLD) {
                #pragma unroll
                for (int j = 0; j < 8; ++j)
                    xv[j] = fmaxf(fmaf(xv[j], ac[k0 + j], ac[128 + k0 + j]), 0.f);
            }
            uint4 w;
            w.x = pk2(xv[0], xv[1]); w.y = pk2(xv[2], xv[3]);
            w.z = pk2(xv[4], xv[5]); w.w = pk2(xv[6], xv[7]);
            *(uint4*)&sX[r * 128 + ((ch ^ (r & 7)) * 8)] = w;
        }
    }
    __syncthreads();

    const int w = tid >> 6, l = tid & 63;
    const int g = l >> 4;
    const int lrow = w * 16 + (l & 15);
    bf16x8 afrag[4];
    #pragma unroll
    for (int kc = 0; kc < 4; ++kc) {
        int ch = kc * 4 + g;
        afrag[kc] = *(const bf16x8*)&sX[lrow * 128 + ((ch ^ (lrow & 7)) * 8)];
    }
    #pragma unroll
    for (int cg = 0; cg < BN / 16; ++cg) {
        const int n = cg * 16 + (l & 15);
        f32x4 acc = {0.f, 0.f, 0.f, 0.f};
        #pragma unroll
        for (int kc = 0; kc < 4; ++kc) {
            int ch = kc * 4 + g;
            bf16x8 bfrag = *(const bf16x8*)&sW[n * 128 + ((ch ^ (n & 7)) * 8)];
            acc = __builtin_amdgcn_mfma_f32_16x16x32_bf16(afrag[kc], bfrag, acc, 0, 0, 0);
        }
        #pragma unroll
        for (int r = 0; r < 4; ++r) {
            int row = row0 + w * 16 + g * 4 + r;
            if (row < N_NODES) {
                if (OUTMODE == 0) {
                    ((u16*)Yv)[(size_t)row * 128 + n] = f2bl(acc[r]);
                } else {
                    if (n < NCLS) ((u16*)Yv)[(size_t)row * NCLS + n] = f2bl(acc[r]);
                }
            }
        }
    }
}

// ---------------- aggregation (128 feats as 64 x u32-pair) ----------------
__global__ __launch_bounds__(64) void agg_kernel(const u32* __restrict__ hin,
                                                 const float* __restrict__ dinv,
                                                 const int* __restrict__ offs,
                                                 const int* __restrict__ csr,
                                                 const float* __restrict__ bias,
                                                 u32* __restrict__ hout) {
    const int i = blockIdx.x;
    const int f = threadIdx.x;
    const float di = dinv[i];
    const int e0 = offs[i], e1 = offs[i + 1];
    float a0l = 0.f, a0h = 0.f, a1l = 0.f, a1h = 0.f;
    float a2l = 0.f, a2h = 0.f, a3l = 0.f, a3h = 0.f;
    int e = e0;
    for (; e + 4 <= e1; e += 4) {
        int s0 = csr[e], s1 = csr[e + 1], s2 = csr[e + 2], s3 = csr[e + 3];
        float d0 = dinv[s0], d1 = dinv[s1], d2 = dinv[s2], d3 = dinv[s3];
        u32 u0 = hin[(size_t)s0 * 64 + f];
        u32 u1 = hin[(size_t)s1 * 64 + f];
        u32 u2 = hin[(size_t)s2 * 64 + f];
        u32 u3 = hin[(size_t)s3 * 64 + f];
        a0l = fmaf(d0, bl_lo(u0), a0l); a0h = fmaf(d0, bl_hi(u0), a0h);
        a1l = fmaf(d1, bl_lo(u1), a1l); a1h = fmaf(d1, bl_hi(u1), a1h);
        a2l = fmaf(d2, bl_lo(u2), a2l); a2h = fmaf(d2, bl_hi(u2), a2h);
        a3l = fmaf(d3, bl_lo(u3), a3l); a3h = fmaf(d3, bl_hi(u3), a3h);
    }
    for (; e < e1; ++e) {
        int s = csr[e];
        float d = dinv[s];
        u32 u = hin[(size_t)s * 64 + f];
        a0l = fmaf(d, bl_lo(u), a0l); a0h = fmaf(d, bl_hi(u), a0h);
    }
    float rl = fmaf((a0l + a1l) + (a2l + a3l), di, bias[2 * f]);
    float rh = fmaf((a0h + a1h) + (a2h + a3h), di, bias[2 * f + 1]);
    hout[(size_t)i * 64 + f] = pk2(rl, rh);
}

// ---------------- BN statistics: wide vectorized + hierarchical reduce ----------------
// grid 512 x 256. Wave handles 4-row quads via uint4 (lane l -> 16B of the 1KB quad).
// Lane groups (l & 15) share an 8-feature column set -> shfl reduce -> LDS -> atomics.
__global__ __launch_bounds__(256) void stats_kernel(const u32* __restrict__ h,
                                                    float* __restrict__ stats) {
    __shared__ float sm[4 * 256];
    const int tid = threadIdx.x;
    const int lane = tid & 63, wv = tid >> 6;
    const int wid = blockIdx.x * 4 + wv;
    const int nw = gridDim.x * 4;
    float s[8] = {}, q[8] = {};
    for (int quad = wid; quad < N_NODES / 4; quad += nw) {
        uint4 v = *(const uint4*)(h + (size_t)quad * 256 + lane * 4);
        float f;
        f = bl_lo(v.x); s[0] += f; q[0] = fmaf(f, f, q[0]);
        f = bl_hi(v.x); s[1] += f; q[1] = fmaf(f, f, q[1]);
        f = bl_lo(v.y); s[2] += f; q[2] = fmaf(f, f, q[2]);
        f = bl_hi(v.y); s[3] += f; q[3] = fmaf(f, f, q[3]);
        f = bl_lo(v.z); s[4] += f; q[4] = fmaf(f, f, q[4]);
        f = bl_hi(v.z); s[5] += f; q[5] = fmaf(f, f, q[5]);
        f = bl_lo(v.w); s[6] += f; q[6] = fmaf(f, f, q[6]);
        f = bl_hi(v.w); s[7] += f; q[7] = fmaf(f, f, q[7]);
    }
    #pragma unroll
    for (int j = 0; j < 8; ++j) {
        s[j] += __shfl_xor(s[j], 16); s[j] += __shfl_xor(s[j], 32);
        q[j] += __shfl_xor(q[j], 16); q[j] += __shfl_xor(q[j], 32);
    }
    if (lane < 16) {
        #pragma unroll
        for (int j = 0; j < 8; ++j) {
            sm[wv * 256 + 8 * lane + j] = s[j];
            sm[wv * 256 + 128 + 8 * lane + j] = q[j];
        }
    }
    __syncthreads();
    float v = sm[tid] + sm[256 + tid] + sm[512 + tid] + sm[768 + tid];
    atomicAdd(&stats[tid], v);
}

__global__ void finalize_kernel(const float* __restrict__ stats, const float* __restrict__ gamma,
                                const float* __restrict__ beta, float* __restrict__ ac) {
    int f = threadIdx.x;
    float mean = stats[f] * (1.f / N_NODES);
    float var = stats[128 + f] * (1.f / N_NODES) - mean * mean;
    float a = gamma[f] * rsqrtf(var + BN_EPS);
    ac[f] = a;
    ac[128 + f] = fmaf(-mean, a, beta[f]);
}

// ---------------- final aggregation (bf16 [N][40]) + log_softmax ----------------
__global__ __launch_bounds__(64) void agg_lsm_kernel(const u32* __restrict__ hin,
                                                     const float* __restrict__ dinv,
                                                     const int* __restrict__ offs,
                                                     const int* __restrict__ csr,
                                                     const float* __restrict__ bias,
                                                     float* __restrict__ out) {
    const int i = blockIdx.x;
    const int lane = threadIdx.x;
    const int es = lane / 20, cp = lane % 20;
    const bool act = es < 3;
    const float di = dinv[i];
    const int e0 = offs[i], e1 = offs[i + 1];
    float al = 0.f, ah = 0.f, bl2 = 0.f, bh2 = 0.f;
    for (int e = e0; e < e1; e += 6) {
        int ee0 = e + es, ee1 = e + 3 + es;
        if (act && ee0 < e1) {
            int s = csr[ee0];
            float d = dinv[s];
            u32 u = hin[(size_t)s * 20 + cp];
            al = fmaf(d, bl_lo(u), al);
            ah = fmaf(d, bl_hi(u), ah);
        }
        if (act && ee1 < e1) {
            int s = csr[ee1];
            float d = dinv[s];
            u32 u = hin[(size_t)s * 20 + cp];
            bl2 = fmaf(d, bl_lo(u), bl2);
            bh2 = fmaf(d, bl_hi(u), bh2);
        }
    }
    al += bl2;
    ah += bh2;
    float al1 = __shfl(al, cp + 20), al2 = __shfl(al, cp + 40);
    float ah1 = __shfl(ah, cp + 20), ah2 = __shfl(ah, cp + 40);
    float lo = fmaf(al + al1 + al2, di, bias[2 * cp]);
    float hi = fmaf(ah + ah1 + ah2, di, bias[2 * cp + 1]);
    float m = (lane < 20) ? fmaxf(lo, hi) : -INFINITY;
    #pragma unroll
    for (int o = 32; o >= 1; o >>= 1) m = fmaxf(m, __shfl_xor(m, o));
    float ex = (lane < 20) ? (__expf(lo - m) + __expf(hi - m)) : 0.f;
    float s = ex;
    #pragma unroll
    for (int o = 32; o >= 1; o >>= 1) s += __shfl_xor(s, o);
    float lse = m + __logf(s);
    if (lane < 20) {
        float2 r = make_float2(lo - lse, hi - lse);
        *((float2*)out + (size_t)i * 20 + cp) = r;
    }
}

extern "C" void kernel_launch(void* const* d_in, const int* in_sizes, int n_in,
                              void* d_out, int out_size, void* d_ws, size_t ws_size,
                              hipStream_t stream) {
    const float* x   = (const float*)d_in[0];
    const int*   ei  = (const int*)d_in[1];
    const float* W1  = (const float*)d_in[2];
    const float* b1  = (const float*)d_in[3];
    const float* g1  = (const float*)d_in[4];
    const float* be1 = (const float*)d_in[5];
    const float* W2  = (const float*)d_in[6];
    const float* b2  = (const float*)d_in[7];
    const float* g2  = (const float*)d_in[8];
    const float* be2 = (const float*)d_in[9];
    const float* W3  = (const float*)d_in[10];
    const float* b3  = (const float*)d_in[11];
    float* out = (float*)d_out;

    char* w = (char*)d_ws;
    size_t off = 0;
    auto take = [&](size_t bytes) {
        void* p = w + off;
        off = (off + bytes + 255) & ~(size_t)255;
        return p;
    };
    float* dinv   = (float*)take((size_t)N_NODES * 4);
    int*   offs   = (int*)take((size_t)(N_NODES + 1) * 4);
    int*   csr    = (int*)take((size_t)(N_EDGES + N_NODES) * 4);
    float* stats1 = (float*)take(256 * 4);
    float* stats2 = (float*)take(256 * 4);
    float* ac1    = (float*)take(256 * 4);
    float* ac2    = (float*)take(256 * 4);
    u16*   Wt1    = (u16*)take(128 * 128 * 2);
    u16*   Wt2    = (u16*)take(128 * 128 * 2);
    u16*   Wt3    = (u16*)take(48 * 128 * 2);
    u32*   bufA   = (u32*)take((size_t)N_NODES * 64 * 4);
    u32*   bufB   = (u32*)take((size_t)N_NODES * 64 * 4);

    int2* ebuf     = (int2*)bufA;
    int*  runstart = (int*)bufB;
    u32*  Y3       = (u32*)bufA;  // bf16 [N][40] layer-3 logits

    hipMemsetAsync(stats1, 0, 256 * 4, stream);
    hipMemsetAsync(stats2, 0, 256 * 4, stream);

    prep_w<<<3, 256, 0, stream>>>(W1, W2, W3, Wt1, Wt2, Wt3);
    binA_kernel<<<GBIN, 256, 0, stream>>>(ei, ebuf, runstart);
    binC_kernel<<<NBKT, 256, 0, stream>>>(ebuf, runstart, csr, offs, dinv);

    const int gm = (N_NODES + 63) / 64;  // 1563
    // layer 1
    mfma_gemm<false, false, 128, 0><<<gm, 256, 0, stream>>>(x, Wt1, nullptr, bufA);
    agg_kernel<<<N_NODES, 64, 0, stream>>>(bufA, dinv, offs, csr, b1, bufB);
    stats_kernel<<<512, 256, 0, stream>>>(bufB, stats1);
    finalize_kernel<<<1, 128, 0, stream>>>(stats1, g1, be1, ac1);
    // layer 2
    mfma_gemm<true, true, 128, 0><<<gm, 256, 0, stream>>>(bufB, Wt2, ac1, bufA);
    agg_kernel<<<N_NODES, 64, 0, stream>>>(bufA, dinv, offs, csr, b2, bufB);
    stats_kernel<<<512, 256, 0, stream>>>(bufB, stats2);
    finalize_kernel<<<1, 128, 0, stream>>>(stats2, g2, be2, ac2);
    // layer 3 (width 40, bf16 out)
    mfma_gemm<true, true, 48, 1><<<gm, 256, 0, stream>>>(bufB, Wt3, ac2, Y3);
    agg_lsm_kernel<<<N_NODES, 64, 0, stream>>>(Y3, dinv, offs, csr, b3, out);
}